// Round 1
// baseline (51.860 us; speedup 1.0000x reference)
//
#include <hip/hip_runtime.h>
#include <hip/hip_bf16.h>

#define NB 4096      // batch
#define NC 100000    // classes
#define ND 256       // feature dim
#define MOM 0.01f

// Kernel 1: bulk copy features_memory -> out (float4 vectorized, grid-stride)
__global__ void mb_copy_kernel(const float4* __restrict__ src,
                               float4* __restrict__ dst, int n4) {
    int i = blockIdx.x * blockDim.x + threadIdx.x;
    int stride = gridDim.x * blockDim.x;
    for (; i < n4; i += stride) dst[i] = src[i];
}

// Kernel 2: one wave per sample; only chain-head waves do work.
// A chain head for class y processes, in index order, every sample j with
// targets[j] == y: row = MOM*row + (1-MOM)*x_j; row /= ||row||.
// Row state: 4 floats per lane (64 lanes * 4 = 256 = ND).
__global__ __launch_bounds__(256) void mb_chain_kernel(
        const float* __restrict__ inputs,
        const int* __restrict__ targets,
        const float* __restrict__ feat_in,
        float* __restrict__ out) {
    int gtid = blockIdx.x * blockDim.x + threadIdx.x;
    int wave = gtid >> 6;
    int lane = threadIdx.x & 63;
    if (wave >= NB) return;

    int y = targets[wave];

    // Head check: does y appear at any index < wave?
    for (int base = 0; base < wave; base += 64) {
        int j = base + lane;
        bool m = (j < wave) && (targets[j] == y);
        if (__ballot(m)) return;  // not the chain head
    }

    // Load initial row from ORIGINAL features_memory (chain starts there).
    float4 row = *reinterpret_cast<const float4*>(
        feat_in + (size_t)y * ND + lane * 4);

    // Walk samples j >= wave with targets[j] == y, strictly in index order.
    for (int base = (wave >> 6) << 6; base < NB; base += 64) {
        int j = base + lane;
        bool m = (j < NB) && (j >= wave) && (targets[j] == y);
        unsigned long long mask = __ballot(m);
        while (mask) {
            int bit = __ffsll((long long)mask) - 1;
            mask &= mask - 1ull;
            int jj = base + bit;
            float4 x = *reinterpret_cast<const float4*>(
                inputs + (size_t)jj * ND + lane * 4);
            row.x = fmaf(MOM, row.x, (1.0f - MOM) * x.x);
            row.y = fmaf(MOM, row.y, (1.0f - MOM) * x.y);
            row.z = fmaf(MOM, row.z, (1.0f - MOM) * x.z);
            row.w = fmaf(MOM, row.w, (1.0f - MOM) * x.w);
            float ss = row.x * row.x + row.y * row.y
                     + row.z * row.z + row.w * row.w;
            #pragma unroll
            for (int off = 32; off > 0; off >>= 1)
                ss += __shfl_xor(ss, off);
            float inv = 1.0f / sqrtf(ss);
            row.x *= inv; row.y *= inv; row.z *= inv; row.w *= inv;
        }
    }

    // Overwrite the copied row with the chain result.
    *reinterpret_cast<float4*>(out + (size_t)y * ND + lane * 4) = row;
}

extern "C" void kernel_launch(void* const* d_in, const int* in_sizes, int n_in,
                              void* d_out, int out_size, void* d_ws, size_t ws_size,
                              hipStream_t stream) {
    const float* inputs  = (const float*)d_in[0];   // [NB, ND]
    const int*   targets = (const int*)d_in[1];     // [NB]
    const float* feat    = (const float*)d_in[2];   // [NC, ND]
    float* out = (float*)d_out;                     // [NC, ND]

    int n4 = (NC * ND) / 4;  // 6,400,000 float4s
    mb_copy_kernel<<<2048, 256, 0, stream>>>(
        (const float4*)feat, (float4*)out, n4);

    // One wave (64 lanes) per sample; 4 waves per 256-thread block.
    mb_chain_kernel<<<NB / 4, 256, 0, stream>>>(inputs, targets, feat, out);
}

// Round 3
// 51.737 us; speedup vs baseline: 1.0024x; 1.0024x over previous
//
#include <hip/hip_runtime.h>
#include <hip/hip_bf16.h>

#define NB 4096      // batch
#define NC 100000    // classes
#define ND 256       // feature dim
#define MOM 0.01f

typedef float f32x4 __attribute__((ext_vector_type(4)));

// Kernel 1: bulk copy features_memory -> out.
// Exact grid: 6250 blocks * 256 threads * 4 float4 = 6,400,000 float4 = NC*ND.
// 4 independent loads then 4 nontemporal stores per thread (MLP=4).
__global__ __launch_bounds__(256) void mb_copy_kernel(
        const f32x4* __restrict__ src, f32x4* __restrict__ dst) {
    int base = blockIdx.x * 1024 + threadIdx.x;
    f32x4 a = src[base];
    f32x4 b = src[base + 256];
    f32x4 c = src[base + 512];
    f32x4 d = src[base + 768];
    __builtin_nontemporal_store(a, dst + base);
    __builtin_nontemporal_store(b, dst + base + 256);
    __builtin_nontemporal_store(c, dst + base + 512);
    __builtin_nontemporal_store(d, dst + base + 768);
}

// Kernel 2: one wave per sample; only chain-head waves do work.
// A chain head for class y processes, in index order, every sample j with
// targets[j] == y: row = MOM*row + (1-MOM)*x_j; row /= ||row||.
// Row state: 4 floats per lane (64 lanes * 4 = 256 = ND).
__global__ __launch_bounds__(256) void mb_chain_kernel(
        const float* __restrict__ inputs,
        const int* __restrict__ targets,
        const float* __restrict__ feat_in,
        float* __restrict__ out) {
    int gtid = blockIdx.x * blockDim.x + threadIdx.x;
    int wave = gtid >> 6;
    int lane = threadIdx.x & 63;
    if (wave >= NB) return;

    int y = targets[wave];

    // Head check: does y appear at any index < wave?
    for (int base = 0; base < wave; base += 64) {
        int j = base + lane;
        bool m = (j < wave) && (targets[j] == y);
        if (__ballot(m)) return;  // not the chain head
    }

    // Load initial row from ORIGINAL features_memory (chain starts there).
    float4 row = *reinterpret_cast<const float4*>(
        feat_in + (size_t)y * ND + lane * 4);

    // Walk samples j >= wave with targets[j] == y, strictly in index order.
    for (int base = (wave >> 6) << 6; base < NB; base += 64) {
        int j = base + lane;
        bool m = (j < NB) && (j >= wave) && (targets[j] == y);
        unsigned long long mask = __ballot(m);
        while (mask) {
            int bit = __ffsll((long long)mask) - 1;
            mask &= mask - 1ull;
            int jj = base + bit;
            float4 x = *reinterpret_cast<const float4*>(
                inputs + (size_t)jj * ND + lane * 4);
            row.x = fmaf(MOM, row.x, (1.0f - MOM) * x.x);
            row.y = fmaf(MOM, row.y, (1.0f - MOM) * x.y);
            row.z = fmaf(MOM, row.z, (1.0f - MOM) * x.z);
            row.w = fmaf(MOM, row.w, (1.0f - MOM) * x.w);
            float ss = row.x * row.x + row.y * row.y
                     + row.z * row.z + row.w * row.w;
            #pragma unroll
            for (int off = 32; off > 0; off >>= 1)
                ss += __shfl_xor(ss, off);
            float inv = 1.0f / sqrtf(ss);
            row.x *= inv; row.y *= inv; row.z *= inv; row.w *= inv;
        }
    }

    // Overwrite the copied row with the chain result.
    *reinterpret_cast<float4*>(out + (size_t)y * ND + lane * 4) = row;
}

extern "C" void kernel_launch(void* const* d_in, const int* in_sizes, int n_in,
                              void* d_out, int out_size, void* d_ws, size_t ws_size,
                              hipStream_t stream) {
    const float* inputs  = (const float*)d_in[0];   // [NB, ND]
    const int*   targets = (const int*)d_in[1];     // [NB]
    const float* feat    = (const float*)d_in[2];   // [NC, ND]
    float* out = (float*)d_out;                     // [NC, ND]

    // NC*ND/4 = 6,400,000 float4s; 6250 blocks * 256 threads * 4 each.
    mb_copy_kernel<<<6250, 256, 0, stream>>>(
        (const f32x4*)feat, (f32x4*)out);

    // One wave (64 lanes) per sample; 4 waves per 256-thread block.
    mb_chain_kernel<<<NB / 4, 256, 0, stream>>>(inputs, targets, feat, out);
}

// Round 4
// 41.909 us; speedup vs baseline: 1.2374x; 1.2345x over previous
//
#include <hip/hip_runtime.h>
#include <hip/hip_bf16.h>

#define NB 4096      // batch
#define NC 100000    // classes
#define ND 256       // feature dim
#define MOM 0.01f

typedef float f32x4 __attribute__((ext_vector_type(4)));

// Kernel 1: bulk copy features_memory -> out.
// Exact grid: 3125 blocks * 256 threads * 8 float4 = 6,400,000 float4 = NC*ND.
// 8 independent loads then 8 nontemporal stores per thread (MLP=8).
__global__ __launch_bounds__(256) void mb_copy_kernel(
        const f32x4* __restrict__ src, f32x4* __restrict__ dst) {
    int base = blockIdx.x * 2048 + threadIdx.x;
    f32x4 v0 = src[base];
    f32x4 v1 = src[base + 256];
    f32x4 v2 = src[base + 512];
    f32x4 v3 = src[base + 768];
    f32x4 v4 = src[base + 1024];
    f32x4 v5 = src[base + 1280];
    f32x4 v6 = src[base + 1536];
    f32x4 v7 = src[base + 1792];
    __builtin_nontemporal_store(v0, dst + base);
    __builtin_nontemporal_store(v1, dst + base + 256);
    __builtin_nontemporal_store(v2, dst + base + 512);
    __builtin_nontemporal_store(v3, dst + base + 768);
    __builtin_nontemporal_store(v4, dst + base + 1024);
    __builtin_nontemporal_store(v5, dst + base + 1280);
    __builtin_nontemporal_store(v6, dst + base + 1536);
    __builtin_nontemporal_store(v7, dst + base + 1792);
}

// Kernel 2: one wave per sample; only chain-head waves do work.
// targets[] staged in LDS once per block (16 KB, shared by 4 waves);
// scans run 256 targets/iteration via int4.
__global__ __launch_bounds__(256) void mb_chain_kernel(
        const float* __restrict__ inputs,
        const int* __restrict__ targets,
        const float* __restrict__ feat_in,
        float* __restrict__ out) {
    __shared__ int4 tg4[NB / 4];  // 1024 * 16B = 16 KB

    int t = threadIdx.x;
    // Cooperative stage: 256 threads * 4 int4 = 1024 int4 = 4096 ints.
    #pragma unroll
    for (int k = 0; k < 4; ++k)
        tg4[t + k * 256] = reinterpret_cast<const int4*>(targets)[t + k * 256];
    __syncthreads();

    const int* tg = reinterpret_cast<const int*>(tg4);
    int wave = (blockIdx.x * 256 + t) >> 6;   // global sample id
    int lane = t & 63;
    int y = tg[wave];

    // Head check: does y appear at any index < wave? (256 targets/iter)
    for (int base = 0; base < wave; base += 256) {
        int4 v = tg4[(base >> 2) + lane];
        int j0 = base + lane * 4;
        bool m = (j0 < wave && v.x == y) | (j0 + 1 < wave && v.y == y)
               | (j0 + 2 < wave && v.z == y) | (j0 + 3 < wave && v.w == y);
        if (__ballot(m)) return;  // not the chain head
    }

    // Load initial row from ORIGINAL features_memory (chain starts there).
    float4 row = *reinterpret_cast<const float4*>(
        feat_in + (size_t)y * ND + lane * 4);

    // Walk samples j >= wave with targets[j] == y, strictly in index order.
    for (int base = wave & ~255; base < NB; base += 256) {
        int4 v = tg4[(base >> 2) + lane];
        int j0 = base + lane * 4;
        unsigned lm = 0;
        lm |= (j0     >= wave && v.x == y) ? 1u : 0u;
        lm |= (j0 + 1 >= wave && v.y == y) ? 2u : 0u;
        lm |= (j0 + 2 >= wave && v.z == y) ? 4u : 0u;
        lm |= (j0 + 3 >= wave && v.w == y) ? 8u : 0u;
        unsigned long long wm = __ballot(lm != 0);
        while (wm) {
            int L = __ffsll((long long)wm) - 1;
            wm &= wm - 1ull;
            unsigned lmL = (unsigned)__shfl((int)lm, L);
            while (lmL) {
                int k = __ffs((int)lmL) - 1;
                lmL &= lmL - 1u;
                int jj = base + L * 4 + k;
                float4 x = *reinterpret_cast<const float4*>(
                    inputs + (size_t)jj * ND + lane * 4);
                row.x = fmaf(MOM, row.x, (1.0f - MOM) * x.x);
                row.y = fmaf(MOM, row.y, (1.0f - MOM) * x.y);
                row.z = fmaf(MOM, row.z, (1.0f - MOM) * x.z);
                row.w = fmaf(MOM, row.w, (1.0f - MOM) * x.w);
                float ss = row.x * row.x + row.y * row.y
                         + row.z * row.z + row.w * row.w;
                #pragma unroll
                for (int off = 32; off > 0; off >>= 1)
                    ss += __shfl_xor(ss, off);
                float inv = 1.0f / sqrtf(ss);
                row.x *= inv; row.y *= inv; row.z *= inv; row.w *= inv;
            }
        }
    }

    // Overwrite the copied row with the chain result.
    *reinterpret_cast<float4*>(out + (size_t)y * ND + lane * 4) = row;
}

extern "C" void kernel_launch(void* const* d_in, const int* in_sizes, int n_in,
                              void* d_out, int out_size, void* d_ws, size_t ws_size,
                              hipStream_t stream) {
    const float* inputs  = (const float*)d_in[0];   // [NB, ND]
    const int*   targets = (const int*)d_in[1];     // [NB]
    const float* feat    = (const float*)d_in[2];   // [NC, ND]
    float* out = (float*)d_out;                     // [NC, ND]

    // NC*ND/4 = 6,400,000 float4s; 3125 blocks * 256 threads * 8 each.
    mb_copy_kernel<<<3125, 256, 0, stream>>>(
        (const f32x4*)feat, (f32x4*)out);

    // One wave (64 lanes) per sample; 4 waves per 256-thread block.
    mb_chain_kernel<<<NB / 4, 256, 0, stream>>>(inputs, targets, feat, out);
}

// Round 5
// 37.668 us; speedup vs baseline: 1.3768x; 1.1126x over previous
//
#include <hip/hip_runtime.h>
#include <hip/hip_bf16.h>

#define NB 4096      // batch
#define NC 100000    // classes
#define ND 256       // feature dim
#define MOM 0.01f

#define CHAIN_BLOCKS (NB / 4)        // 1024 blocks, 4 waves each = 4096 waves
#define COPY_BLOCKS  ((NC * ND / 4) / 2048)  // 3125 blocks * 2048 float4

typedef float f32x4 __attribute__((ext_vector_type(4)));

// Fused kernel.
//  Blocks [0, CHAIN_BLOCKS): chain path — one wave per sample; chain-head
//    waves compute the final row for their class and write it to out.
//  Blocks [CHAIN_BLOCKS, +COPY_BLOCKS): copy path — copy 32 aligned rows of
//    feat -> out, SKIPPING rows whose class appears in targets (those are
//    owned by chain waves). Write sets are disjoint => no ordering needed.
__global__ __launch_bounds__(256) void mb_fused_kernel(
        const float* __restrict__ inputs,
        const int* __restrict__ targets,
        const float* __restrict__ feat_in,
        float* __restrict__ out) {
    __shared__ int4 tg4[NB / 4];   // 16 KB, chain path
    __shared__ int flags[32];      // copy path
    int t = threadIdx.x;

    if (blockIdx.x < CHAIN_BLOCKS) {
        // ---- chain path ----
        // Stage all targets into LDS (256 threads * 4 int4).
        #pragma unroll
        for (int k = 0; k < 4; ++k)
            tg4[t + k * 256] =
                reinterpret_cast<const int4*>(targets)[t + k * 256];
        __syncthreads();

        const int* tg = reinterpret_cast<const int*>(tg4);
        int wave = (blockIdx.x * 256 + t) >> 6;   // global sample id
        int lane = t & 63;
        int y = tg[wave];

        // Head check: does y appear at any index < wave? (256 targets/iter)
        for (int base = 0; base < wave; base += 256) {
            int4 v = tg4[(base >> 2) + lane];
            int j0 = base + lane * 4;
            bool m = (j0 < wave && v.x == y) | (j0 + 1 < wave && v.y == y)
                   | (j0 + 2 < wave && v.z == y) | (j0 + 3 < wave && v.w == y);
            if (__ballot(m)) return;  // not the chain head
        }

        // Initial row from ORIGINAL features_memory.
        float4 row = *reinterpret_cast<const float4*>(
            feat_in + (size_t)y * ND + lane * 4);

        // Walk samples j >= wave with targets[j] == y, in index order.
        for (int base = wave & ~255; base < NB; base += 256) {
            int4 v = tg4[(base >> 2) + lane];
            int j0 = base + lane * 4;
            unsigned lm = 0;
            lm |= (j0     >= wave && v.x == y) ? 1u : 0u;
            lm |= (j0 + 1 >= wave && v.y == y) ? 2u : 0u;
            lm |= (j0 + 2 >= wave && v.z == y) ? 4u : 0u;
            lm |= (j0 + 3 >= wave && v.w == y) ? 8u : 0u;
            unsigned long long wm = __ballot(lm != 0);
            while (wm) {
                int L = __ffsll((long long)wm) - 1;
                wm &= wm - 1ull;
                unsigned lmL = (unsigned)__shfl((int)lm, L);
                while (lmL) {
                    int k = __ffs((int)lmL) - 1;
                    lmL &= lmL - 1u;
                    int jj = base + L * 4 + k;
                    float4 x = *reinterpret_cast<const float4*>(
                        inputs + (size_t)jj * ND + lane * 4);
                    row.x = fmaf(MOM, row.x, (1.0f - MOM) * x.x);
                    row.y = fmaf(MOM, row.y, (1.0f - MOM) * x.y);
                    row.z = fmaf(MOM, row.z, (1.0f - MOM) * x.z);
                    row.w = fmaf(MOM, row.w, (1.0f - MOM) * x.w);
                    float ss = row.x * row.x + row.y * row.y
                             + row.z * row.z + row.w * row.w;
                    #pragma unroll
                    for (int off = 32; off > 0; off >>= 1)
                        ss += __shfl_xor(ss, off);
                    float inv = 1.0f / sqrtf(ss);
                    row.x *= inv; row.y *= inv; row.z *= inv; row.w *= inv;
                }
            }
        }

        *reinterpret_cast<float4*>(out + (size_t)y * ND + lane * 4) = row;
    } else {
        // ---- copy path ----
        int cb = blockIdx.x - CHAIN_BLOCKS;
        int r0 = cb * 32;  // first of the 32 rows this block covers

        if (t < 32) flags[t] = 0;
        __syncthreads();

        // Which of our 32 rows appear in targets? 256 threads * 16 targets.
        const int4* tgg = reinterpret_cast<const int4*>(targets);
        #pragma unroll
        for (int k = 0; k < 4; ++k) {
            int4 v = tgg[t + k * 256];
            if ((unsigned)(v.x - r0) < 32u) flags[v.x - r0] = 1;
            if ((unsigned)(v.y - r0) < 32u) flags[v.y - r0] = 1;
            if ((unsigned)(v.z - r0) < 32u) flags[v.z - r0] = 1;
            if ((unsigned)(v.w - r0) < 32u) flags[v.w - r0] = 1;
        }
        __syncthreads();

        const f32x4* src = reinterpret_cast<const f32x4*>(feat_in);
        f32x4* dst = reinterpret_cast<f32x4*>(out);
        size_t base = (size_t)cb * 2048 + t;
        f32x4 v0 = src[base];
        f32x4 v1 = src[base + 256];
        f32x4 v2 = src[base + 512];
        f32x4 v3 = src[base + 768];
        f32x4 v4 = src[base + 1024];
        f32x4 v5 = src[base + 1280];
        f32x4 v6 = src[base + 1536];
        f32x4 v7 = src[base + 1792];
        int w = t >> 6;  // local row of access k is w + 4k
        if (!flags[w     ]) dst[base]        = v0;
        if (!flags[w +  4]) dst[base +  256] = v1;
        if (!flags[w +  8]) dst[base +  512] = v2;
        if (!flags[w + 12]) dst[base +  768] = v3;
        if (!flags[w + 16]) dst[base + 1024] = v4;
        if (!flags[w + 20]) dst[base + 1280] = v5;
        if (!flags[w + 24]) dst[base + 1536] = v6;
        if (!flags[w + 28]) dst[base + 1792] = v7;
    }
}

extern "C" void kernel_launch(void* const* d_in, const int* in_sizes, int n_in,
                              void* d_out, int out_size, void* d_ws, size_t ws_size,
                              hipStream_t stream) {
    const float* inputs  = (const float*)d_in[0];   // [NB, ND]
    const int*   targets = (const int*)d_in[1];     // [NB]
    const float* feat    = (const float*)d_in[2];   // [NC, ND]
    float* out = (float*)d_out;                     // [NC, ND]

    mb_fused_kernel<<<CHAIN_BLOCKS + COPY_BLOCKS, 256, 0, stream>>>(
        inputs, targets, feat, out);
}

// Round 6
// 37.402 us; speedup vs baseline: 1.3866x; 1.0071x over previous
//
#include <hip/hip_runtime.h>
#include <hip/hip_bf16.h>

#define NB 4096      // batch
#define NC 100000    // classes
#define ND 256       // feature dim
#define MOM 0.01f

#define CHAIN_BLOCKS (NB / 4)        // 1024 blocks, 4 waves each = 4096 waves
#define COPY_BLOCKS  ((NC * ND / 4) / 2048)  // 3125 blocks * 2048 float4

typedef float f32x4 __attribute__((ext_vector_type(4)));

// Fused kernel.
//  Blocks [0, CHAIN_BLOCKS): chain path — one wave per sample; chain-head
//    waves compute the final row for their class and write it to out.
//  Blocks [CHAIN_BLOCKS, +COPY_BLOCKS): copy path — copy 32 aligned rows of
//    feat -> out, SKIPPING rows whose class appears in targets (those are
//    owned by chain waves). Write sets are disjoint => no ordering needed.
//  Store policy: NT stores for the bulk copy (out never re-read; keep L3
//  exclusively for feat so reads become L3-resident across graph replays).
__global__ __launch_bounds__(256) void mb_fused_kernel(
        const float* __restrict__ inputs,
        const int* __restrict__ targets,
        const float* __restrict__ feat_in,
        float* __restrict__ out) {
    __shared__ int4 tg4[NB / 4];   // 16 KB, chain path
    __shared__ int flags[32];      // copy path
    int t = threadIdx.x;

    if (blockIdx.x < CHAIN_BLOCKS) {
        // ---- chain path ----
        // Stage all targets into LDS (256 threads * 4 int4).
        #pragma unroll
        for (int k = 0; k < 4; ++k)
            tg4[t + k * 256] =
                reinterpret_cast<const int4*>(targets)[t + k * 256];
        __syncthreads();

        const int* tg = reinterpret_cast<const int*>(tg4);
        int wave = (blockIdx.x * 256 + t) >> 6;   // global sample id
        int lane = t & 63;
        int y = tg[wave];

        // Head check: does y appear at any index < wave? (256 targets/iter)
        for (int base = 0; base < wave; base += 256) {
            int4 v = tg4[(base >> 2) + lane];
            int j0 = base + lane * 4;
            bool m = (j0 < wave && v.x == y) | (j0 + 1 < wave && v.y == y)
                   | (j0 + 2 < wave && v.z == y) | (j0 + 3 < wave && v.w == y);
            if (__ballot(m)) return;  // not the chain head
        }

        // Initial row from ORIGINAL features_memory.
        float4 row = *reinterpret_cast<const float4*>(
            feat_in + (size_t)y * ND + lane * 4);

        // Walk samples j >= wave with targets[j] == y, in index order.
        for (int base = wave & ~255; base < NB; base += 256) {
            int4 v = tg4[(base >> 2) + lane];
            int j0 = base + lane * 4;
            unsigned lm = 0;
            lm |= (j0     >= wave && v.x == y) ? 1u : 0u;
            lm |= (j0 + 1 >= wave && v.y == y) ? 2u : 0u;
            lm |= (j0 + 2 >= wave && v.z == y) ? 4u : 0u;
            lm |= (j0 + 3 >= wave && v.w == y) ? 8u : 0u;
            unsigned long long wm = __ballot(lm != 0);
            while (wm) {
                int L = __ffsll((long long)wm) - 1;
                wm &= wm - 1ull;
                unsigned lmL = (unsigned)__shfl((int)lm, L);
                while (lmL) {
                    int k = __ffs((int)lmL) - 1;
                    lmL &= lmL - 1u;
                    int jj = base + L * 4 + k;
                    float4 x = *reinterpret_cast<const float4*>(
                        inputs + (size_t)jj * ND + lane * 4);
                    row.x = fmaf(MOM, row.x, (1.0f - MOM) * x.x);
                    row.y = fmaf(MOM, row.y, (1.0f - MOM) * x.y);
                    row.z = fmaf(MOM, row.z, (1.0f - MOM) * x.z);
                    row.w = fmaf(MOM, row.w, (1.0f - MOM) * x.w);
                    float ss = row.x * row.x + row.y * row.y
                             + row.z * row.z + row.w * row.w;
                    #pragma unroll
                    for (int off = 32; off > 0; off >>= 1)
                        ss += __shfl_xor(ss, off);
                    float inv = 1.0f / sqrtf(ss);
                    row.x *= inv; row.y *= inv; row.z *= inv; row.w *= inv;
                }
            }
        }

        *reinterpret_cast<float4*>(out + (size_t)y * ND + lane * 4) = row;
    } else {
        // ---- copy path ----
        int cb = blockIdx.x - CHAIN_BLOCKS;
        int r0 = cb * 32;  // first of the 32 rows this block covers

        if (t < 32) flags[t] = 0;
        __syncthreads();

        // Which of our 32 rows appear in targets? 256 threads * 16 targets.
        const int4* tgg = reinterpret_cast<const int4*>(targets);
        #pragma unroll
        for (int k = 0; k < 4; ++k) {
            int4 v = tgg[t + k * 256];
            if ((unsigned)(v.x - r0) < 32u) flags[v.x - r0] = 1;
            if ((unsigned)(v.y - r0) < 32u) flags[v.y - r0] = 1;
            if ((unsigned)(v.z - r0) < 32u) flags[v.z - r0] = 1;
            if ((unsigned)(v.w - r0) < 32u) flags[v.w - r0] = 1;
        }
        __syncthreads();

        const f32x4* src = reinterpret_cast<const f32x4*>(feat_in);
        f32x4* dst = reinterpret_cast<f32x4*>(out);
        size_t base = (size_t)cb * 2048 + t;
        f32x4 v0 = src[base];
        f32x4 v1 = src[base + 256];
        f32x4 v2 = src[base + 512];
        f32x4 v3 = src[base + 768];
        f32x4 v4 = src[base + 1024];
        f32x4 v5 = src[base + 1280];
        f32x4 v6 = src[base + 1536];
        f32x4 v7 = src[base + 1792];
        int w = t >> 6;  // local row of access k is w + 4k
        if (!flags[w     ]) __builtin_nontemporal_store(v0, dst + base);
        if (!flags[w +  4]) __builtin_nontemporal_store(v1, dst + base + 256);
        if (!flags[w +  8]) __builtin_nontemporal_store(v2, dst + base + 512);
        if (!flags[w + 12]) __builtin_nontemporal_store(v3, dst + base + 768);
        if (!flags[w + 16]) __builtin_nontemporal_store(v4, dst + base + 1024);
        if (!flags[w + 20]) __builtin_nontemporal_store(v5, dst + base + 1280);
        if (!flags[w + 24]) __builtin_nontemporal_store(v6, dst + base + 1536);
        if (!flags[w + 28]) __builtin_nontemporal_store(v7, dst + base + 1792);
    }
}

extern "C" void kernel_launch(void* const* d_in, const int* in_sizes, int n_in,
                              void* d_out, int out_size, void* d_ws, size_t ws_size,
                              hipStream_t stream) {
    const float* inputs  = (const float*)d_in[0];   // [NB, ND]
    const int*   targets = (const int*)d_in[1];     // [NB]
    const float* feat    = (const float*)d_in[2];   // [NC, ND]
    float* out = (float*)d_out;                     // [NC, ND]

    mb_fused_kernel<<<CHAIN_BLOCKS + COPY_BLOCKS, 256, 0, stream>>>(
        inputs, targets, feat, out);
}